// Round 6
// baseline (110.093 us; speedup 1.0000x reference)
//
#include <hip/hip_runtime.h>
#include <math.h>

#define SM_WSUM 0
#define SM_RWS  1
#define SM_Q00  2
#define SM_Z2   4
#define SM_BS   16
#define SM_W    48
#define SM_G    148
#define SM_GV   248
#define SM_BW   260
#define SM_SIZE 292

// arena offsets (floats). Phase P and Phase A usages are barrier-separated.
#define AR_W    0     // a_w[100]
#define AR_BW   104   // a_bw[30]
#define AR_C    136   // a_C[100]
#define AR_HI   240   // a_Hi[100]
#define AR_G    340   // a_G[100]
#define AR_T    440   // a_T[100]
#define AR_GV   544   // a_gv[10]
#define AR_HT   560   // a_Ht[10]
#define AR_Z    576   // a_z[10]
#define AR_F    0     // sF [4][90]
#define AR_QL   360   // sQl [4][56]
#define AR_D    592   // sD [4][12]
#define AR_G3   640   // sG3 [4][9]
#define AR_SIZE 768

__host__ __device__ constexpr int TRI(int p,int q){ return p*10-(p*(p+1))/2+q; } // p<=q
__host__ __device__ constexpr int SIDX(int a,int b){ return (a<=b)?TRI(a,b):TRI(b,a); }
__host__ __device__ constexpr int LTRI(int i,int j){ return i*(i+1)/2+j; }       // j<=i

template<int CTRL>
__device__ __forceinline__ float dpp_add(float v){
  int s = __builtin_amdgcn_mov_dpp(__float_as_int(v), CTRL, 0xF, 0xF, true);
  return v + __int_as_float(s);
}
// 16-lane group sum (DPP rows are 16 lanes; groups = lanes [16i..16i+15])
__device__ __forceinline__ float gsum16(float v){
  v = dpp_add<0xB1>(v);    // quad xor1
  v = dpp_add<0x4E>(v);    // quad xor2
  v = dpp_add<0x141>(v);   // row_half_mirror (8-lane exchange)
  v = dpp_add<0x140>(v);   // row_mirror (16-lane exchange)
  return v;
}

__global__ __launch_bounds__(64,2) void pace_fused(const float* __restrict__ y,
                                                   const float* __restrict__ w,
                                                   const float* __restrict__ mk,
                                                   float* __restrict__ out){
  __shared__ __attribute__((aligned(16))) float sc[3600];     // coef rows [n][36]
  __shared__ float sm[SM_SIZE];
  __shared__ __attribute__((aligned(16))) float arena[AR_SIZE];
  const int tid  = threadIdx.x;
  const int sub  = tid & 15;
  const int item = tid >> 4;
  const int gb   = blockIdx.x*4 + item;
  const float* yb = y + gb*300;

  // ================= Phase P: per-block precompute (identical across blocks) =================
  {
    float* a_w  = arena+AR_W;
    float* a_bw = arena+AR_BW;
    float* a_C  = arena+AR_C;
    float* a_Hi = arena+AR_HI;
    float* a_G  = arena+AR_G;
    float* a_T  = arena+AR_T;
    float* a_gv = arena+AR_GV;
    float* a_Ht = arena+AR_HT;
    float* a_z  = arena+AR_Z;

    for (int i=tid;i<100;i+=64) a_w[i]=w[i];
    __syncthreads();

    float av = a_w[tid] + ((tid<36)? a_w[tid+64] : 0.f);
    #pragma unroll
    for (int m=32;m;m>>=1) av += __shfl_xor(av,m);
    const float wsum = av;
    const float rws  = 1.0f/av;

    if (tid<30){   // b_w rows from global mk
      const float4* p=(const float4*)(mk+tid*100);
      const float4* q=(const float4*)a_w;
      float acc=0;
      #pragma unroll 5
      for (int j=0;j<25;j++){ float4 x=p[j], yv=q[j];
        acc=fmaf(x.x,yv.x,acc); acc=fmaf(x.y,yv.y,acc);
        acc=fmaf(x.z,yv.z,acc); acc=fmaf(x.w,yv.w,acc); }
      a_bw[tid]=acc*rws;
    }
    __syncthreads();

    // coef rows: sc[n][0]=w ; sc[n][1+r]=w[n]*(mk[r,n]-bw[r]) ; pads zero
    for (int i=tid;i<3000;i+=64){
      int r=i/100, n=i-100*r;
      sc[n*36+1+r]=a_w[n]*(mk[i]-a_bw[r]);
    }
    for (int i=tid;i<100;i+=64){
      sc[i*36]=a_w[i];
      sc[i*36+31]=0.f; sc[i*36+32]=0.f; sc[i*36+33]=0.f;
      sc[i*36+34]=0.f; sc[i*36+35]=0.f;
    }
    // C = bar_B^T bar_B from global mk (L2-hot)
    for (int e=tid;e<100;e+=64){
      int k=e/10, k2=e-10*k;
      float acc=0;
      #pragma unroll
      for (int j=0;j<3;j++){
        const float4* pa=(const float4*)(mk+(3*k+j)*100);
        const float4* pb=(const float4*)(mk+(3*k2+j)*100);
        const float4* pw=(const float4*)a_w;
        float ba=a_bw[3*k+j], bb=a_bw[3*k2+j];
        #pragma unroll 5
        for (int q=0;q<25;q++){
          float4 xa=pa[q], xb=pb[q], xw=pw[q];
          acc=fmaf(xw.x*(xa.x-ba),(xb.x-bb),acc);
          acc=fmaf(xw.y*(xa.y-ba),(xb.y-bb),acc);
          acc=fmaf(xw.z*(xa.z-ba),(xb.z-bb),acc);
          acc=fmaf(xw.w*(xa.w-ba),(xb.w-bb),acc);
        }
      }
      a_C[e]=acc;
    }
    __syncthreads();

    // Gauss-Jordan inversion of 2(C+I): lanes 0..9 own rows (register rows + shuffles)
    float R[20];
    {
      int row=(tid<10)? tid : 0;
      #pragma unroll
      for (int c=0;c<10;c++) R[c]=2.0f*(a_C[row*10+c]+(c==row?1.0f:0.0f));
      #pragma unroll
      for (int c=0;c<10;c++) R[10+c]=(c==row)?1.0f:0.0f;
    }
    #pragma unroll
    for (int p=0;p<10;p++){
      float appv=__shfl(R[p],p);
      float ra=1.0f/appv;
      float fr=R[p];
      #pragma unroll
      for (int c=0;c<20;c++){
        float pc=__shfl(R[c],p)*ra;
        R[c]=(tid==p)? pc : fmaf(-fr,pc,R[c]);
      }
    }
    float ht=0.f;
    if (tid<10){
      #pragma unroll
      for (int c=0;c<10;c++){ a_Hi[tid*10+c]=R[10+c]; ht+=R[10+c]; }
      a_Ht[tid]=ht;
    }
    float hv=(tid<10)? ht : 0.f;
    #pragma unroll
    for (int m=32;m;m>>=1) hv+=__shfl_xor(hv,m);
    const float rden=1.0f/hv;
    if (tid<10) a_gv[tid]=ht*rden;
    __syncthreads();
    for (int e=tid;e<100;e+=64){ int r=e/10,c=e-10*r; a_G[e]=a_Hi[e]-a_Ht[r]*a_Ht[c]*rden; }
    __syncthreads();
    for (int e=tid;e<100;e+=64){           // T = (C+I)G
      int r=e/10,c=e-10*r; float acc=0;
      #pragma unroll
      for (int j=0;j<10;j++) acc+=(a_C[r*10+j]+(r==j?1.0f:0.0f))*a_G[j*10+c];
      a_T[e]=acc;
    }
    __syncthreads();
    for (int e=tid;e<100;e+=64){           // W = 4G(C+I)G - 4G ; emit G
      int r=e/10,c=e-10*r; float acc=0;
      #pragma unroll
      for (int j=0;j<10;j++) acc+=a_G[r*10+j]*a_T[j*10+c];
      sm[SM_W+e]=4.0f*acc-4.0f*a_G[e];
      sm[SM_G+e]=a_G[e];
    }
    if (tid<10){                            // z = (C+I)g
      float acc=0;
      #pragma unroll
      for (int j=0;j<10;j++) acc+=(a_C[tid*10+j]+(tid==j?1.0f:0.0f))*a_gv[j];
      a_z[tid]=acc;
    }
    __syncthreads();
    if (tid<10){                            // z2 = 2Gz - g
      float acc=0;
      #pragma unroll
      for (int j=0;j<10;j++) acc+=a_G[tid*10+j]*a_z[j];
      sm[SM_Z2+tid]=2.0f*acc-a_gv[tid];
    }
    float qv=0.f;
    if (tid<10){                            // q00 = g^T C g + g.g
      float acc=0;
      #pragma unroll
      for (int c=0;c<10;c++) acc+=a_C[tid*10+c]*a_gv[c];
      qv=a_gv[tid]*acc+a_gv[tid]*a_gv[tid];
    }
    #pragma unroll
    for (int m=32;m;m>>=1) qv+=__shfl_xor(qv,m);
    if (tid==0){ sm[SM_WSUM]=wsum; sm[SM_RWS]=rws; sm[SM_Q00]=qv; sm[3]=0.f; }
    if (tid<30){                            // bs = column sums of c
      float acc=0;
      for (int n=0;n<100;n++) acc+=sc[n*36+1+tid];
      sm[SM_BS+tid]=acc;
    }
    if (tid<10) sm[SM_GV+tid]=a_gv[tid];
    if (tid<30) sm[SM_BW+tid]=a_bw[tid];
    __syncthreads();   // Phase P done; arena reusable
  }

  // ================= Phase A: 16 lanes per item =================
  float* sF  = arena+AR_F;
  float* sQl = arena+AR_QL;
  float* sD  = arena+AR_D;
  float* sG3 = arena+AR_G3;

  float F0[90];
  #pragma unroll
  for (int i=0;i<90;i++) F0[i]=0.f;
  float swy0=0,swy1=0,swy2=0,s00=0,s01=0,s02=0,s11=0,s12=0,s22=0;

  auto point=[&](int n){
    float y0=yb[n], y1=yb[100+n], y2=yb[200+n];
    float c[32];
    const float4* cp=(const float4*)&sc[n*36];
    #pragma unroll
    for (int r=0;r<8;r++) ((float4*)c)[r]=cp[r];
    float wn=c[0];
    float wy0=wn*y0,wy1=wn*y1,wy2=wn*y2;
    swy0+=wy0;swy1+=wy1;swy2+=wy2;
    s00+=wy0*y0;s01+=wy0*y1;s02+=wy0*y2;s11+=wy1*y1;s12+=wy1*y2;s22+=wy2*y2;
    #pragma unroll
    for (int k=0;k<10;k++){
      #pragma unroll
      for (int j=0;j<3;j++){
        float bcv=c[1+k*3+j];
        F0[k*9+j*3+0]+=bcv*y0;
        F0[k*9+j*3+1]+=bcv*y1;
        F0[k*9+j*3+2]+=bcv*y2;
      }
    }
  };
  #pragma unroll
  for (int m=0;m<6;m++) point(sub+16*m);
  if (sub<4) point(96+sub);

  // 16-lane reductions (DPP)
  #pragma unroll
  for (int e=0;e<90;e++) F0[e]=gsum16(F0[e]);
  swy0=gsum16(swy0); swy1=gsum16(swy1); swy2=gsum16(swy2);
  s00=gsum16(s00); s01=gsum16(s01); s02=gsum16(s02);
  s11=gsum16(s11); s12=gsum16(s12); s22=gsum16(s22);

  const float wsum=sm[SM_WSUM], rws=sm[SM_RWS];
  const float yw0=swy0*rws, yw1=swy1*rws, yw2=swy2*rws;
  float G3r[9];
  G3r[0]=s00-wsum*yw0*yw0; G3r[4]=s11-wsum*yw1*yw1; G3r[8]=s22-wsum*yw2*yw2;
  G3r[1]=G3r[3]=s01-wsum*yw0*yw1;
  G3r[2]=G3r[6]=s02-wsum*yw0*yw2;
  G3r[5]=G3r[7]=s12-wsum*yw1*yw2;
  #pragma unroll
  for (int k=0;k<10;k++){
    float bs0=sm[SM_BS+k*3+0],bs1=sm[SM_BS+k*3+1],bs2=sm[SM_BS+k*3+2];
    F0[k*9+0]-=yw0*bs0; F0[k*9+1]-=yw1*bs0; F0[k*9+2]-=yw2*bs0;
    F0[k*9+3]-=yw0*bs1; F0[k*9+4]-=yw1*bs1; F0[k*9+5]-=yw2*bs1;
    F0[k*9+6]-=yw0*bs2; F0[k*9+7]-=yw1*bs2; F0[k*9+8]-=yw2*bs2;
  }
  if (sub==0){
    #pragma unroll
    for (int e=0;e<90;e++) sF[item*90+e]=F0[e];
    #pragma unroll
    for (int e=0;e<9;e++) sG3[item*9+e]=G3r[e];
  }
  __syncthreads();

  // ---- Q assembly: subs 0..8 own a column; sub 9 writes q00 ----
  if (sub<9){
    int mp=sub;
    float fcol[10], t2[10];
    #pragma unroll
    for (int k=0;k<10;k++) fcol[k]=sF[item*90+k*9+mp];
    #pragma unroll
    for (int k=0;k<10;k++){
      float acc=0;
      #pragma unroll
      for (int k2=0;k2<10;k2++) acc+=sm[SM_W+k*10+k2]*fcol[k2];
      t2[k]=acc;
    }
    float he=0;
    #pragma unroll
    for (int k=0;k<10;k++) he+=sm[SM_Z2+k]*fcol[k];
    sQl[item*56 + 1+mp]=he;
    #pragma unroll 1
    for (int m=0;m<=mp;m++){
      float gd=sG3[item*9+(m%3)*3+(mp%3)];
      float acc=((m/3)==(mp/3))? gd : 0.f;
      #pragma unroll
      for (int k=0;k<10;k++) acc+=sF[item*90+k*9+m]*t2[k];
      int p=1+m, q=1+mp;
      sQl[item*56 + p*10-((p*(p+1))>>1)+q]=acc;
    }
  }
  if (sub==9) sQl[item*56 + 0]=sm[SM_Q00];
  __syncthreads();

  // ================= eigen (redundant across the item's 16 lanes) =================
  float A[55];
  #pragma unroll
  for (int e=0;e<55;e++) A[e]=sQl[item*56+e];
  float dd[10], ee[9];
  #pragma unroll
  for (int k=0;k<8;k++){
    float nrm2=0.f;
    #pragma unroll
    for (int i=1;i<10;i++){ if (i<k+1) continue; float xi=A[SIDX(i,k)]; nrm2=fmaf(xi,xi,nrm2); }
    float x0=A[SIDX(k+1,k)];
    float nr=sqrtf(nrm2);
    float alpha=-copysignf(nr,x0);
    bool ok=nrm2>1e-30f;
    float v1=x0-alpha;
    float vtv=-2.0f*alpha*v1;
    float bh=ok?2.0f*__builtin_amdgcn_rcpf(vtv):0.f;
    ee[k]=ok?alpha:x0;
    float vv[10];
    #pragma unroll
    for (int i=0;i<10;i++) vv[i]=(i<k+1)?0.f:((i==k+1)?v1:A[SIDX(i,k)]);
    float p[10];
    #pragma unroll
    for (int i=0;i<10;i++){
      if (i<k+1){ p[i]=0.f; continue; }
      float acc=0;
      #pragma unroll
      for (int j=1;j<10;j++){ if (j<k+1) continue; acc+=A[SIDX(i,j)]*vv[j]; }
      p[i]=bh*acc;
    }
    float Kc=0.f;
    #pragma unroll
    for (int i=1;i<10;i++){ if (i<k+1) continue; Kc=fmaf(vv[i],p[i],Kc); }
    Kc*=0.5f*bh;
    float wv[10];
    #pragma unroll
    for (int i=0;i<10;i++) wv[i]=p[i]-Kc*vv[i];
    #pragma unroll
    for (int i=1;i<10;i++){
      if (i<k+1) continue;
      #pragma unroll
      for (int j=1;j<10;j++){
        if (j<i) continue;
        A[TRI(i,j)]-=vv[i]*wv[j]+wv[i]*vv[j];
      }
    }
  }
  ee[8]=A[TRI(8,9)];
  #pragma unroll
  for (int i=0;i<10;i++) dd[i]=A[TRI(i,i)];
  float esq[9];
  #pragma unroll
  for (int i=0;i<9;i++) esq[i]=ee[i]*ee[i];

  // Gershgorin bracket, 17-way cooperative bisection (16 probes/iter), 5 iters
  float scaleT=0.f, lo=1e30f, hi=1e30f;
  #pragma unroll
  for (int i=0;i<10;i++){
    float r=((i>0)?fabsf(ee[i-1]):0.f)+((i<9)?fabsf(ee[i]):0.f);
    scaleT=fmaxf(scaleT,fabsf(dd[i])+r);
    lo=fminf(lo,dd[i]-r);
    hi=fminf(hi,dd[i]);
  }
  hi+=1e-6f*scaleT+1e-30f;
  const float pm=1e-12f*scaleT+1e-37f;
  const float r17=1.0f/17.0f;
  #pragma unroll 1
  for (int it=0;it<5;++it){
    float delta=(hi-lo)*r17;
    float mid=lo+delta*(float)(sub+1);
    float q=dd[0]-mid;
    q=(fabsf(q)<pm)?((q<0.f)?-pm:pm):q;
    int cnt=(q<0.f);
    #pragma unroll
    for (int i=1;i<10;i++){
      q=dd[i]-mid-esq[i-1]*__builtin_amdgcn_rcpf(q);
      q=(fabsf(q)<pm)?((q<0.f)?-pm:pm):q;
      cnt+=(q<0.f);
    }
    unsigned long long bal=__ballot(cnt>0);
    unsigned gm=(unsigned)((bal>>(item*16))&0xFFFFull);
    int js=gm?(__ffs((int)gm)-1):16;
    float nhi=(js<16)?(lo+delta*(float)(js+1)):hi;
    lo=lo+delta*(float)js;
    hi=nhi;
  }
  const float sigma=lo-1e-5f*scaleT-1e-30f;   // cnt(sigma)==0; margin caps amplification
  const float pmL=1e-8f*scaleT+1e-37f;

  // Cholesky of (Q - sigma I) from LDS; overflow rails throughout
  float Lc[55], rd[10];
  #pragma unroll
  for (int i=0;i<10;i++){
    #pragma unroll
    for (int j=0;j<10;j++){
      if (j>i) continue;
      float a=sQl[item*56+SIDX(j,i)]-((i==j)?sigma:0.f);
      #pragma unroll
      for (int t2=0;t2<9;t2++){
        if (t2>=j) continue;
        a-=Lc[LTRI(i,t2)]*Lc[LTRI(j,t2)];
      }
      if (j<i) Lc[LTRI(i,j)]=a*rd[j];
      else { a=fmaxf(a,pmL); rd[i]=rsqrtf(a); Lc[LTRI(i,i)]=a*rd[i]; }
    }
  }
  float xv[10];
  #pragma unroll
  for (int i=0;i<10;i++) xv[i]=1.f;
  #pragma unroll 1
  for (int itr=0;itr<3;++itr){
    #pragma unroll
    for (int i=0;i<10;i++){
      float acc=xv[i];
      #pragma unroll
      for (int j=0;j<9;j++){ if (j>=i) continue; acc-=Lc[LTRI(i,j)]*xv[j]; }
      acc*=rd[i];
      xv[i]=fminf(fmaxf(acc,-1e15f),1e15f);
    }
    #pragma unroll
    for (int i=9;i>=0;i--){
      float acc=xv[i];
      #pragma unroll
      for (int j=9;j>0;j--){ if (j<=i) continue; acc-=Lc[LTRI(j,i)]*xv[j]; }
      acc*=rd[i];
      xv[i]=fminf(fmaxf(acc,-1e15f),1e15f);
    }
    float nn=0.f;
    #pragma unroll
    for (int i=0;i<10;i++) nn=fmaf(xv[i],xv[i],nn);
    nn=fmaxf(nn,1e-30f);
    float sc2=rsqrtf(nn);
    #pragma unroll
    for (int i=0;i<10;i++) xv[i]*=sc2;
  }
  float r0=1.0f/xv[0];
  float vn[10];
  vn[0]=1.f;
  #pragma unroll
  for (int m=1;m<10;m++) vn[m]=xv[m]*r0;

  // ================= epilogue (sub-split; barriers fence sD read/write) =================
  if (sub<10){
    float dv=0;
    #pragma unroll
    for (int m=0;m<9;m++) dv+=vn[1+m]*sF[item*90+sub*9+m];
    sD[item*12+sub]=dv;
  }
  __syncthreads();
  float dreg[10];
  #pragma unroll
  for (int k=0;k<10;k++) dreg[k]=sD[item*12+k];
  __syncthreads();
  if (sub<10){
    float acc=0;
    #pragma unroll
    for (int k2=0;k2<10;k2++) acc+=sm[SM_G+sub*10+k2]*dreg[k2];
    float cvk=2.0f*acc+sm[SM_GV+sub];
    out[98304+gb*10+sub]=cvk;
    sD[item*12+sub]=cvk;
  }
  __syncthreads();
  float cvr[10];
  #pragma unroll
  for (int k=0;k<10;k++) cvr[k]=sD[item*12+k];
  float e0=0,e1=0,e2=0;
  #pragma unroll
  for (int k=0;k<10;k++){
    e0+=sm[SM_BW+k*3+0]*cvr[k];
    e1+=sm[SM_BW+k*3+1]*cvr[k];
    e2+=sm[SM_BW+k*3+2]*cvr[k];
  }
  if (sub==10){
    #pragma unroll
    for (int i=0;i<3;i++)
      #pragma unroll
      for (int j=0;j<3;j++)
        out[gb*9+i*3+j]=vn[1+3*j+i];
  }
  if (sub==11){
    out[73728+gb*3+0]=yw0-(vn[1]*e0+vn[4]*e1+vn[7]*e2);
    out[73728+gb*3+1]=yw1-(vn[2]*e0+vn[5]*e1+vn[8]*e2);
    out[73728+gb*3+2]=yw2-(vn[3]*e0+vn[6]*e1+vn[9]*e2);
  }
}

extern "C" void kernel_launch(void* const* d_in, const int* in_sizes, int n_in,
                              void* d_out, int out_size, void* d_ws, size_t ws_size,
                              hipStream_t stream) {
  const float* y  = (const float*)d_in[0];   // (8192,3,100)
  const float* w  = (const float*)d_in[1];   // (100,1)
  const float* mk = (const float*)d_in[2];   // (10,3,100)
  float* out = (float*)d_out;                // R(8192*9) | t(8192*3) | c(8192*10)
  pace_fused<<<2048, 64, 0, stream>>>(y, w, mk, out);
}